// Round 1
// baseline (2273.477 us; speedup 1.0000x reference)
//
#include <hip/hip_runtime.h>

#define N_TOK 8192
#define C_DIM 2048
#define F_DIM 5632
#define E_NUM 8

#define BM 128
#define BN 128
#define BK 64
#define MAXT 136   // max total M-tiles over experts: 16384/128 + 8 (ceil slack)

typedef __attribute__((ext_vector_type(8))) short bf16x8;
typedef __attribute__((ext_vector_type(4))) float f32x4;

typedef const void __attribute__((address_space(1)))* gas1;
typedef void __attribute__((address_space(3)))* las3;

__device__ __forceinline__ unsigned short f2bf(float f){
  union { float f; unsigned u; } v; v.f = f;
  unsigned r = v.u + 0x7FFFu + ((v.u >> 16) & 1u);   // RNE
  return (unsigned short)(r >> 16);
}

__device__ __forceinline__ void glds16(const unsigned short* g, unsigned short* l){
  // 16B direct global->LDS; LDS dest is wave-uniform base + lane*16 (pass base), global addr per-lane
  __builtin_amdgcn_global_load_lds((gas1)g, (las3)l, 16, 0, 0);
}

// ---------------- x fp32 -> bf16 ----------------
__global__ void k_cvt_x(const float* __restrict__ x, unsigned short* __restrict__ xb, int n4){
  int i = blockIdx.x * blockDim.x + threadIdx.x;
  int stride = gridDim.x * blockDim.x;
  const float4* xi = (const float4*)x;
  ushort4* xo = (ushort4*)xb;
  for (; i < n4; i += stride){
    float4 v = xi[i];
    ushort4 o; o.x = f2bf(v.x); o.y = f2bf(v.y); o.z = f2bf(v.z); o.w = f2bf(v.w);
    xo[i] = o;
  }
}

// ------- weight convert + transpose: in [R][Cc] fp32 -> out [Cc][R] bf16, per z-slab -------
__global__ void k_tcvt_w(const float* __restrict__ in, unsigned short* __restrict__ out, int R, int Cc){
  __shared__ float t[32][33];
  size_t slab = (size_t)blockIdx.z * R * Cc;
  in += slab; out += slab;
  int c0 = blockIdx.x * 32, r0 = blockIdx.y * 32;
  int tx = threadIdx.x, ty = threadIdx.y;
  #pragma unroll
  for (int i = 0; i < 4; ++i){
    int r = ty + i*8;
    t[r][tx] = in[(size_t)(r0 + r) * Cc + c0 + tx];
  }
  __syncthreads();
  #pragma unroll
  for (int i = 0; i < 4; ++i){
    int cr = ty + i*8;
    out[(size_t)(c0 + cr) * R + r0 + tx] = f2bf(t[tx][cr]);
  }
}

// ---------------- router: logits -> top2 -> sigmoid renorm; build expert lists ----------------
__global__ void k_router(const float* __restrict__ x, const float* __restrict__ Wg,
                         int* __restrict__ cnt, int* __restrict__ list, float* __restrict__ p_slot)
{
  int wid = threadIdx.x >> 6, lane = threadIdx.x & 63;
  int n = blockIdx.x * 4 + wid;                 // one wave per token
  int e = lane >> 3, sub = lane & 7;            // 8 lanes per expert
  const float* xr = x + (size_t)n * C_DIM;
  float acc = 0.f;
  for (int i = sub; i < C_DIM; i += 8)
    acc += xr[i] * Wg[i*E_NUM + e];
  acc += __shfl_xor(acc, 1);
  acc += __shfl_xor(acc, 2);
  acc += __shfl_xor(acc, 4);                    // 8-lane group sum -> logit[e] in every group lane
  float lg[E_NUM];
  #pragma unroll
  for (int j = 0; j < E_NUM; ++j) lg[j] = __shfl(acc, j*8);  // all lanes participate
  if (lane == 0){
    int e1 = 0; float m1 = lg[0];
    #pragma unroll
    for (int j = 1; j < E_NUM; ++j) if (lg[j] > m1){ m1 = lg[j]; e1 = j; }
    int e2 = -1; float m2 = -1e30f;
    #pragma unroll
    for (int j = 0; j < E_NUM; ++j) if (j != e1 && lg[j] > m2){ m2 = lg[j]; e2 = j; }
    // softmax + top2 + renorm == sigmoid over top-2 logit gap
    float p1 = 1.f / (1.f + __expf(m2 - m1));
    float p2 = 1.f - p1;
    int pos1 = atomicAdd(&cnt[e1], 1);
    list[e1*N_TOK + pos1] = n*2;
    p_slot[n*2] = p1;
    int pos2 = atomicAdd(&cnt[e2], 1);
    list[e2*N_TOK + pos2] = n*2 + 1;
    p_slot[n*2 + 1] = p2;
  }
}

// ---------------- prefix / tile table ----------------
__global__ void k_prefix(const int* __restrict__ cnt, int* __restrict__ meta){
  if (threadIdx.x == 0 && blockIdx.x == 0){
    int acc = 0, t = 0;
    for (int e = 0; e < E_NUM; ++e){
      meta[e] = acc; acc += cnt[e];
      int nt = (cnt[e] + BM - 1) / BM;
      for (int i = 0; i < nt; ++i) meta[16 + t++] = (e << 16) | i;
    }
    meta[8] = t;
  }
}

// ---------------- GEMM1: h = silu(xg@W1) * (xg@W3), grouped over experts ----------------
__global__ __launch_bounds__(256, 2) void k_gemm1(
    const unsigned short* __restrict__ xb,
    const unsigned short* __restrict__ wb1,   // [E][F][C] bf16 (transposed)
    const unsigned short* __restrict__ wb3,   // [E][F][C]
    unsigned short* __restrict__ h,           // [2N+1024][F] bf16
    const int* __restrict__ cnt,
    const int* __restrict__ meta,
    const int* __restrict__ list)
{
  int t = blockIdx.x;
  if (t >= meta[8]) return;
  int info = meta[16 + t];
  int e  = info >> 16;
  int m0 = (info & 0xffff) * BM;
  int n0 = blockIdx.y * BN;                  // f offset
  int count = cnt[e];
  int hbase = meta[e];

  __shared__ __align__(16) unsigned short sA [BM*BK];
  __shared__ __align__(16) unsigned short sB1[BN*BK];
  __shared__ __align__(16) unsigned short sB3[BN*BK];

  int tid = threadIdx.x;
  int lane = tid & 63, wid = tid >> 6;
  int wm = wid >> 1, wn = wid & 1;

  // staging geometry: byte = it*4096 + tid*16 -> row = it*32 + tid/8, colk = (tid&7)*8 elems
  const unsigned short* aS[4];
  const unsigned short* bS[4];
  int colk = (tid & 7) * 8;
  #pragma unroll
  for (int it = 0; it < 4; ++it){
    int row = it*32 + (tid >> 3);
    int ts  = list[e*N_TOK + m0 + row];
    int tok = (ts >> 1) & (N_TOK - 1);        // mask keeps pad-row garbage in-bounds
    aS[it] = xb + (size_t)tok * C_DIM + colk;
    bS[it] = wb1 + ((size_t)e*F_DIM + n0 + row) * C_DIM + colk;
  }
  ptrdiff_t w31 = wb3 - wb1;                  // uniform offset between W1t and W3t

  f32x4 zero = {0.f, 0.f, 0.f, 0.f};
  f32x4 acc1[4][4], acc3[4][4];
  #pragma unroll
  for (int mi = 0; mi < 4; ++mi)
    #pragma unroll
    for (int ni = 0; ni < 4; ++ni){ acc1[mi][ni] = zero; acc3[mi][ni] = zero; }

  int ldsbase = wid * 512;                    // elements within each 2048-elem it-chunk

  for (int kt = 0; kt < C_DIM/BK; ++kt){
    int ko = kt * BK;
    #pragma unroll
    for (int it = 0; it < 4; ++it){
      glds16(aS[it] + ko,        &sA [it*2048 + ldsbase]);
      glds16(bS[it] + ko,        &sB1[it*2048 + ldsbase]);
      glds16(bS[it] + w31 + ko,  &sB3[it*2048 + ldsbase]);
    }
    __syncthreads();
    #pragma unroll
    for (int ks = 0; ks < 2; ++ks){
      bf16x8 aF[4], b1F[4], b3F[4];
      int kb = ks*32 + ((lane >> 4) * 8);
      #pragma unroll
      for (int mi = 0; mi < 4; ++mi){
        int r = wm*64 + mi*16 + (lane & 15);
        aF[mi] = *(const bf16x8*)&sA[r*BK + kb];
      }
      #pragma unroll
      for (int ni = 0; ni < 4; ++ni){
        int fr = wn*64 + ni*16 + (lane & 15);
        b1F[ni] = *(const bf16x8*)&sB1[fr*BK + kb];
        b3F[ni] = *(const bf16x8*)&sB3[fr*BK + kb];
      }
      #pragma unroll
      for (int mi = 0; mi < 4; ++mi)
        #pragma unroll
        for (int ni = 0; ni < 4; ++ni){
          acc1[mi][ni] = __builtin_amdgcn_mfma_f32_16x16x32_bf16(aF[mi], b1F[ni], acc1[mi][ni], 0, 0, 0);
          acc3[mi][ni] = __builtin_amdgcn_mfma_f32_16x16x32_bf16(aF[mi], b3F[ni], acc3[mi][ni], 0, 0, 0);
        }
    }
    __syncthreads();
  }

  // epilogue: D row = (lane>>4)*4 + r, col = lane&15  (verified C/D layout)
  #pragma unroll
  for (int mi = 0; mi < 4; ++mi){
    #pragma unroll
    for (int r = 0; r < 4; ++r){
      int rloc = m0 + wm*64 + mi*16 + ((lane >> 4) * 4) + r;
      if (rloc < count){
        unsigned short* hrow = h + (size_t)(hbase + rloc) * F_DIM + n0 + wn*64 + (lane & 15);
        #pragma unroll
        for (int ni = 0; ni < 4; ++ni){
          float v1 = acc1[mi][ni][r];
          float v3 = acc3[mi][ni][r];
          float hv = (v1 / (1.f + __expf(-v1))) * v3;   // silu(v1)*v3
          hrow[ni*16] = f2bf(hv);
        }
      }
    }
  }
}

// ---------------- GEMM2: ybuf[slot] = p * (h @ W2t), grouped ----------------
__global__ __launch_bounds__(256, 2) void k_gemm2(
    const unsigned short* __restrict__ h,
    const unsigned short* __restrict__ wb2,   // [E][C][F] bf16 (transposed)
    float* __restrict__ ybuf,                 // [2N][C]
    const int* __restrict__ cnt,
    const int* __restrict__ meta,
    const int* __restrict__ list,
    const float* __restrict__ p_slot)
{
  int t = blockIdx.x;
  if (t >= meta[8]) return;
  int info = meta[16 + t];
  int e  = info >> 16;
  int m0 = (info & 0xffff) * BM;
  int n0 = blockIdx.y * BN;                   // c_out offset
  int count = cnt[e];
  int hbase = meta[e];

  __shared__ __align__(16) unsigned short sA[BM*BK];
  __shared__ __align__(16) unsigned short sB[BN*BK];

  int tid = threadIdx.x;
  int lane = tid & 63, wid = tid >> 6;
  int wm = wid >> 1, wn = wid & 1;

  const unsigned short* aS[4];
  const unsigned short* bS[4];
  int colk = (tid & 7) * 8;
  #pragma unroll
  for (int it = 0; it < 4; ++it){
    int row = it*32 + (tid >> 3);
    aS[it] = h   + (size_t)(hbase + m0 + row) * F_DIM + colk;
    bS[it] = wb2 + ((size_t)e*C_DIM + n0 + row) * F_DIM + colk;
  }

  f32x4 zero = {0.f, 0.f, 0.f, 0.f};
  f32x4 acc[4][4];
  #pragma unroll
  for (int mi = 0; mi < 4; ++mi)
    #pragma unroll
    for (int ni = 0; ni < 4; ++ni) acc[mi][ni] = zero;

  int ldsbase = wid * 512;

  for (int kt = 0; kt < F_DIM/BK; ++kt){
    int ko = kt * BK;
    #pragma unroll
    for (int it = 0; it < 4; ++it){
      glds16(aS[it] + ko, &sA[it*2048 + ldsbase]);
      glds16(bS[it] + ko, &sB[it*2048 + ldsbase]);
    }
    __syncthreads();
    #pragma unroll
    for (int ks = 0; ks < 2; ++ks){
      bf16x8 aF[4], bF[4];
      int kb = ks*32 + ((lane >> 4) * 8);
      #pragma unroll
      for (int mi = 0; mi < 4; ++mi){
        int r = wm*64 + mi*16 + (lane & 15);
        aF[mi] = *(const bf16x8*)&sA[r*BK + kb];
      }
      #pragma unroll
      for (int ni = 0; ni < 4; ++ni){
        int cr = wn*64 + ni*16 + (lane & 15);
        bF[ni] = *(const bf16x8*)&sB[cr*BK + kb];
      }
      #pragma unroll
      for (int mi = 0; mi < 4; ++mi)
        #pragma unroll
        for (int ni = 0; ni < 4; ++ni)
          acc[mi][ni] = __builtin_amdgcn_mfma_f32_16x16x32_bf16(aF[mi], bF[ni], acc[mi][ni], 0, 0, 0);
    }
    __syncthreads();
  }

  #pragma unroll
  for (int mi = 0; mi < 4; ++mi){
    #pragma unroll
    for (int r = 0; r < 4; ++r){
      int rloc = m0 + wm*64 + mi*16 + ((lane >> 4) * 4) + r;
      if (rloc < count){
        int ts = list[e*N_TOK + rloc];
        float p = p_slot[ts];
        float* yr = ybuf + (size_t)ts * C_DIM + n0 + wn*64 + (lane & 15);
        #pragma unroll
        for (int ni = 0; ni < 4; ++ni)
          yr[ni*16] = p * acc[mi][ni][r];
      }
    }
  }
}

// ---------------- combine: y[n] = ybuf[2n] + ybuf[2n+1] ----------------
__global__ void k_combine(const float* __restrict__ ybuf, float* __restrict__ y){
  int i = blockIdx.x * blockDim.x + threadIdx.x;
  int stride = gridDim.x * blockDim.x;
  const float4* yb = (const float4*)ybuf;
  float4* yo = (float4*)y;
  const int total = N_TOK * (C_DIM/4);
  for (; i < total; i += stride){
    int n = i >> 9;            // C_DIM/4 = 512
    int c = i & 511;
    float4 a = yb[(size_t)n*1024 + c];
    float4 b = yb[(size_t)n*1024 + 512 + c];
    float4 o; o.x = a.x+b.x; o.y = a.y+b.y; o.z = a.z+b.z; o.w = a.w+b.w;
    yo[i] = o;
  }
}

extern "C" void kernel_launch(void* const* d_in, const int* in_sizes, int n_in,
                              void* d_out, int out_size, void* d_ws, size_t ws_size,
                              hipStream_t stream)
{
  const float* x  = (const float*)d_in[0];
  const float* Wg = (const float*)d_in[1];
  const float* W1 = (const float*)d_in[2];
  const float* W3 = (const float*)d_in[3];
  const float* W2 = (const float*)d_in[4];
  float* y = (float*)d_out;
  (void)in_sizes; (void)n_in; (void)out_size; (void)ws_size;

  char* ws = (char*)d_ws;
  size_t o = 0;
  auto alloc = [&](size_t bytes)->char* {
    char* p = ws + o;
    o = (o + bytes + 255) & ~(size_t)255;
    return p;
  };
  int*    cnt    = (int*)  alloc(E_NUM * 4);
  int*    meta   = (int*)  alloc(160 * 4);
  float*  p_slot = (float*)alloc((size_t)2*N_TOK * 4);
  int*    list   = (int*)  alloc((size_t)E_NUM*N_TOK * 4);
  unsigned short* xb  = (unsigned short*)alloc((size_t)N_TOK*C_DIM * 2);
  unsigned short* wb1 = (unsigned short*)alloc((size_t)E_NUM*C_DIM*F_DIM * 2);
  unsigned short* wb3 = (unsigned short*)alloc((size_t)E_NUM*C_DIM*F_DIM * 2);
  unsigned short* wb2 = (unsigned short*)alloc((size_t)E_NUM*C_DIM*F_DIM * 2);
  unsigned short* h   = (unsigned short*)alloc((size_t)(2*N_TOK + 1024)*F_DIM * 2);
  float*  ybuf = (float*)alloc((size_t)2*N_TOK*C_DIM * 4);
  // total ws usage ~918 MB

  hipMemsetAsync(cnt, 0, E_NUM * 4, stream);
  k_cvt_x<<<4096, 256, 0, stream>>>(x, xb, (N_TOK*C_DIM)/4);
  // W1,W3: [E][C][F] -> [E][F][C]
  k_tcvt_w<<<dim3(F_DIM/32, C_DIM/32, E_NUM), dim3(32,8), 0, stream>>>(W1, wb1, C_DIM, F_DIM);
  k_tcvt_w<<<dim3(F_DIM/32, C_DIM/32, E_NUM), dim3(32,8), 0, stream>>>(W3, wb3, C_DIM, F_DIM);
  // W2: [E][F][C] -> [E][C][F]
  k_tcvt_w<<<dim3(C_DIM/32, F_DIM/32, E_NUM), dim3(32,8), 0, stream>>>(W2, wb2, F_DIM, C_DIM);
  k_router<<<N_TOK/4, 256, 0, stream>>>(x, Wg, cnt, list, p_slot);
  k_prefix<<<1, 64, 0, stream>>>(cnt, meta);
  k_gemm1<<<dim3(MAXT, F_DIM/BN), 256, 0, stream>>>(xb, wb1, wb3, h, cnt, meta, list);
  k_gemm2<<<dim3(MAXT, C_DIM/BN), 256, 0, stream>>>(h, wb2, ybuf, cnt, meta, list, p_slot);
  k_combine<<<4096, 256, 0, stream>>>(ybuf, y);
}

// Round 2
// 1995.826 us; speedup vs baseline: 1.1391x; 1.1391x over previous
//
#include <hip/hip_runtime.h>

#define N_TOK 8192
#define C_DIM 2048
#define F_DIM 5632
#define E_NUM 8

#define BM 128
#define BN 128
#define BK 64
#define MAXT 136                 // max total M-tiles over experts
#define GRID1 (MAXT * (F_DIM/BN))   // 136*44 = 5984, divisible by 8
#define GRID2 (MAXT * (C_DIM/BN))   // 136*16 = 2176, divisible by 8

typedef __attribute__((ext_vector_type(8))) short bf16x8;
typedef __attribute__((ext_vector_type(4))) float f32x4;

typedef const void __attribute__((address_space(1)))* gas1;
typedef void __attribute__((address_space(3)))* las3;

__device__ __forceinline__ unsigned short f2bf(float f){
  union { float f; unsigned u; } v; v.f = f;
  unsigned r = v.u + 0x7FFFu + ((v.u >> 16) & 1u);   // RNE
  return (unsigned short)(r >> 16);
}

__device__ __forceinline__ void glds16(const unsigned short* g, unsigned short* l){
  __builtin_amdgcn_global_load_lds((gas1)g, (las3)l, 16, 0, 0);
}

// ---------------- x fp32 -> bf16 ----------------
__global__ void k_cvt_x(const float* __restrict__ x, unsigned short* __restrict__ xb, int n4){
  int i = blockIdx.x * blockDim.x + threadIdx.x;
  int stride = gridDim.x * blockDim.x;
  const float4* xi = (const float4*)x;
  ushort4* xo = (ushort4*)xb;
  for (; i < n4; i += stride){
    float4 v = xi[i];
    ushort4 o; o.x = f2bf(v.x); o.y = f2bf(v.y); o.z = f2bf(v.z); o.w = f2bf(v.w);
    xo[i] = o;
  }
}

// ------- weight convert + transpose: in [R][Cc] fp32 -> out [Cc][R] bf16, per z-slab -------
// 64x64 tile: loads 256B-coalesced, stores 128B-coalesced bf16
__global__ void k_tcvt_w(const float* __restrict__ in, unsigned short* __restrict__ out, int R, int Cc){
  __shared__ float t[64][65];
  size_t slab = (size_t)blockIdx.z * R * Cc;
  in += slab; out += slab;
  int c0 = blockIdx.x * 64, r0 = blockIdx.y * 64;
  int tx = threadIdx.x, ty = threadIdx.y;     // 64 x 4
  #pragma unroll
  for (int i = 0; i < 16; ++i){
    int r = ty + i*4;
    t[r][tx] = in[(size_t)(r0 + r) * Cc + c0 + tx];
  }
  __syncthreads();
  #pragma unroll
  for (int i = 0; i < 16; ++i){
    int cr = ty + i*4;
    out[(size_t)(c0 + cr) * R + r0 + tx] = f2bf(t[tx][cr]);
  }
}

// ---------------- router ----------------
__global__ void k_router(const float* __restrict__ x, const float* __restrict__ Wg,
                         int* __restrict__ cnt, int* __restrict__ list, float* __restrict__ p_slot)
{
  int wid = threadIdx.x >> 6, lane = threadIdx.x & 63;
  int n = blockIdx.x * 4 + wid;                 // one wave per token
  int e = lane >> 3, sub = lane & 7;
  const float* xr = x + (size_t)n * C_DIM;
  float acc = 0.f;
  for (int i = sub; i < C_DIM; i += 8)
    acc += xr[i] * Wg[i*E_NUM + e];
  acc += __shfl_xor(acc, 1);
  acc += __shfl_xor(acc, 2);
  acc += __shfl_xor(acc, 4);
  float lg[E_NUM];
  #pragma unroll
  for (int j = 0; j < E_NUM; ++j) lg[j] = __shfl(acc, j*8);
  if (lane == 0){
    int e1 = 0; float m1 = lg[0];
    #pragma unroll
    for (int j = 1; j < E_NUM; ++j) if (lg[j] > m1){ m1 = lg[j]; e1 = j; }
    int e2 = -1; float m2 = -1e30f;
    #pragma unroll
    for (int j = 0; j < E_NUM; ++j) if (j != e1 && lg[j] > m2){ m2 = lg[j]; e2 = j; }
    float p1 = 1.f / (1.f + __expf(m2 - m1));
    float p2 = 1.f - p1;
    int pos1 = atomicAdd(&cnt[e1], 1);
    list[e1*N_TOK + pos1] = n*2;
    p_slot[n*2] = p1;
    int pos2 = atomicAdd(&cnt[e2], 1);
    list[e2*N_TOK + pos2] = n*2 + 1;
    p_slot[n*2 + 1] = p2;
  }
}

// ---------------- prefix / tile table ----------------
__global__ void k_prefix(const int* __restrict__ cnt, int* __restrict__ meta){
  if (threadIdx.x == 0 && blockIdx.x == 0){
    int acc = 0, t = 0;
    for (int e = 0; e < E_NUM; ++e){
      meta[e] = acc; acc += cnt[e];
      int nt = (cnt[e] + BM - 1) / BM;
      for (int i = 0; i < nt; ++i) meta[16 + t++] = (e << 16) | i;
    }
    meta[8] = t;
  }
}

// ---------------- GEMM1: h = silu(xg@W1) * (xg@W3), grouped ----------------
__global__ __launch_bounds__(256, 2) void k_gemm1(
    const unsigned short* __restrict__ xb,
    const unsigned short* __restrict__ wb1,   // [E][F][C] bf16
    const unsigned short* __restrict__ wb3,   // [E][F][C]
    unsigned short* __restrict__ h,           // [2N+1024][F] bf16
    const int* __restrict__ cnt,
    const int* __restrict__ meta,
    const int* __restrict__ list)
{
  // XCD-chunked swizzle: work w, t fastest (same-expert m-tiles stay on one XCD -> B panel L2 reuse)
  int o = blockIdx.x;
  int w = (o & 7) * (GRID1/8) + (o >> 3);
  int t = w % MAXT;
  int n0 = (w / MAXT) * BN;
  if (t >= meta[8]) return;
  int info = meta[16 + t];
  int e  = info >> 16;
  int m0 = (info & 0xffff) * BM;
  int count = cnt[e];
  int hbase = meta[e];

  __shared__ __align__(16) unsigned short sA [BM*BK];
  __shared__ __align__(16) unsigned short sB1[BN*BK];
  __shared__ __align__(16) unsigned short sB3[BN*BK];

  int tid = threadIdx.x;
  int lane = tid & 63, wid = tid >> 6;
  int wm = wid >> 1, wn = wid & 1;

  // staging: LDS stays linear (byte = it*4096 + tid*16); SOURCE chunk is XOR-swizzled (rule #21)
  // LDS slot (row=tid>>3, chunk=tid&7) receives global chunk (tid&7)^(row&7)
  const unsigned short* aS[4];
  const unsigned short* bS[4];
  int swz = (((tid & 7) ^ ((tid >> 3) & 7))) * 8;   // element offset in 64-elem row
  #pragma unroll
  for (int it = 0; it < 4; ++it){
    int row = it*32 + (tid >> 3);
    int ts  = list[e*N_TOK + m0 + row];
    int tok = (ts >> 1) & (N_TOK - 1);
    aS[it] = xb + (size_t)tok * C_DIM + swz;
    bS[it] = wb1 + ((size_t)e*F_DIM + n0 + row) * C_DIM + swz;
  }
  ptrdiff_t w31 = wb3 - wb1;

  f32x4 zero = {0.f, 0.f, 0.f, 0.f};
  f32x4 acc1[4][4], acc3[4][4];
  #pragma unroll
  for (int mi = 0; mi < 4; ++mi)
    #pragma unroll
    for (int ni = 0; ni < 4; ++ni){ acc1[mi][ni] = zero; acc3[mi][ni] = zero; }

  int ldsbase = wid * 512;

  for (int kt = 0; kt < C_DIM/BK; ++kt){
    int ko = kt * BK;
    #pragma unroll
    for (int it = 0; it < 4; ++it){
      glds16(aS[it] + ko,        &sA [it*2048 + ldsbase]);
      glds16(bS[it] + ko,        &sB1[it*2048 + ldsbase]);
      glds16(bS[it] + w31 + ko,  &sB3[it*2048 + ldsbase]);
    }
    __syncthreads();
    #pragma unroll
    for (int ks = 0; ks < 2; ++ks){
      bf16x8 aF[4], b1F[4], b3F[4];
      // swizzled read: chunk = (ks*4 + lane>>4) ^ (row&7); row&7 == lane&7 for all fragments
      int xr = ((ks*4 + (lane >> 4)) ^ (lane & 7)) * 8;
      #pragma unroll
      for (int mi = 0; mi < 4; ++mi){
        int r = wm*64 + mi*16 + (lane & 15);
        aF[mi] = *(const bf16x8*)&sA[r*BK + xr];
      }
      #pragma unroll
      for (int ni = 0; ni < 4; ++ni){
        int fr = wn*64 + ni*16 + (lane & 15);
        b1F[ni] = *(const bf16x8*)&sB1[fr*BK + xr];
        b3F[ni] = *(const bf16x8*)&sB3[fr*BK + xr];
      }
      #pragma unroll
      for (int mi = 0; mi < 4; ++mi)
        #pragma unroll
        for (int ni = 0; ni < 4; ++ni){
          acc1[mi][ni] = __builtin_amdgcn_mfma_f32_16x16x32_bf16(aF[mi], b1F[ni], acc1[mi][ni], 0, 0, 0);
          acc3[mi][ni] = __builtin_amdgcn_mfma_f32_16x16x32_bf16(aF[mi], b3F[ni], acc3[mi][ni], 0, 0, 0);
        }
    }
    __syncthreads();
  }

  #pragma unroll
  for (int mi = 0; mi < 4; ++mi){
    #pragma unroll
    for (int r = 0; r < 4; ++r){
      int rloc = m0 + wm*64 + mi*16 + ((lane >> 4) * 4) + r;
      if (rloc < count){
        unsigned short* hrow = h + (size_t)(hbase + rloc) * F_DIM + n0 + wn*64 + (lane & 15);
        #pragma unroll
        for (int ni = 0; ni < 4; ++ni){
          float v1 = acc1[mi][ni][r];
          float v3 = acc3[mi][ni][r];
          float hv = (v1 / (1.f + __expf(-v1))) * v3;
          hrow[ni*16] = f2bf(hv);
        }
      }
    }
  }
}

// ---------------- GEMM2: y[token] += p * (h @ W2t), grouped, atomic combine ----------------
__global__ __launch_bounds__(256, 2) void k_gemm2(
    const unsigned short* __restrict__ h,
    const unsigned short* __restrict__ wb2,   // [E][C][F] bf16
    float* __restrict__ y,                    // [N][C] fp32, pre-zeroed
    const int* __restrict__ cnt,
    const int* __restrict__ meta,
    const int* __restrict__ list,
    const float* __restrict__ p_slot)
{
  int o = blockIdx.x;
  int w = (o & 7) * (GRID2/8) + (o >> 3);
  int t = w % MAXT;
  int n0 = (w / MAXT) * BN;
  if (t >= meta[8]) return;
  int info = meta[16 + t];
  int e  = info >> 16;
  int m0 = (info & 0xffff) * BM;
  int count = cnt[e];
  int hbase = meta[e];

  __shared__ __align__(16) unsigned short sA[BM*BK];
  __shared__ __align__(16) unsigned short sB[BN*BK];

  int tid = threadIdx.x;
  int lane = tid & 63, wid = tid >> 6;
  int wm = wid >> 1, wn = wid & 1;

  const unsigned short* aS[4];
  const unsigned short* bS[4];
  int swz = (((tid & 7) ^ ((tid >> 3) & 7))) * 8;
  #pragma unroll
  for (int it = 0; it < 4; ++it){
    int row = it*32 + (tid >> 3);
    aS[it] = h   + (size_t)(hbase + m0 + row) * F_DIM + swz;
    bS[it] = wb2 + ((size_t)e*C_DIM + n0 + row) * F_DIM + swz;
  }

  f32x4 zero = {0.f, 0.f, 0.f, 0.f};
  f32x4 acc[4][4];
  #pragma unroll
  for (int mi = 0; mi < 4; ++mi)
    #pragma unroll
    for (int ni = 0; ni < 4; ++ni) acc[mi][ni] = zero;

  int ldsbase = wid * 512;

  for (int kt = 0; kt < F_DIM/BK; ++kt){
    int ko = kt * BK;
    #pragma unroll
    for (int it = 0; it < 4; ++it){
      glds16(aS[it] + ko, &sA[it*2048 + ldsbase]);
      glds16(bS[it] + ko, &sB[it*2048 + ldsbase]);
    }
    __syncthreads();
    #pragma unroll
    for (int ks = 0; ks < 2; ++ks){
      bf16x8 aF[4], bF[4];
      int xr = ((ks*4 + (lane >> 4)) ^ (lane & 7)) * 8;
      #pragma unroll
      for (int mi = 0; mi < 4; ++mi){
        int r = wm*64 + mi*16 + (lane & 15);
        aF[mi] = *(const bf16x8*)&sA[r*BK + xr];
      }
      #pragma unroll
      for (int ni = 0; ni < 4; ++ni){
        int cr = wn*64 + ni*16 + (lane & 15);
        bF[ni] = *(const bf16x8*)&sB[cr*BK + xr];
      }
      #pragma unroll
      for (int mi = 0; mi < 4; ++mi)
        #pragma unroll
        for (int ni = 0; ni < 4; ++ni)
          acc[mi][ni] = __builtin_amdgcn_mfma_f32_16x16x32_bf16(aF[mi], bF[ni], acc[mi][ni], 0, 0, 0);
    }
    __syncthreads();
  }

  // epilogue: two commutative fp32 adds per y element starting from exact 0 -> deterministic
  #pragma unroll
  for (int mi = 0; mi < 4; ++mi){
    #pragma unroll
    for (int r = 0; r < 4; ++r){
      int rloc = m0 + wm*64 + mi*16 + ((lane >> 4) * 4) + r;
      if (rloc < count){
        int ts = list[e*N_TOK + rloc];
        float p = p_slot[ts];
        int tok = ts >> 1;
        float* yr = y + (size_t)tok * C_DIM + n0 + wn*64 + (lane & 15);
        #pragma unroll
        for (int ni = 0; ni < 4; ++ni)
          atomicAdd(&yr[ni*16], p * acc[mi][ni][r]);
      }
    }
  }
}

extern "C" void kernel_launch(void* const* d_in, const int* in_sizes, int n_in,
                              void* d_out, int out_size, void* d_ws, size_t ws_size,
                              hipStream_t stream)
{
  const float* x  = (const float*)d_in[0];
  const float* Wg = (const float*)d_in[1];
  const float* W1 = (const float*)d_in[2];
  const float* W3 = (const float*)d_in[3];
  const float* W2 = (const float*)d_in[4];
  float* y = (float*)d_out;
  (void)in_sizes; (void)n_in; (void)out_size; (void)ws_size;

  char* ws = (char*)d_ws;
  size_t o = 0;
  auto alloc = [&](size_t bytes)->char* {
    char* p = ws + o;
    o = (o + bytes + 255) & ~(size_t)255;
    return p;
  };
  int*    cnt    = (int*)  alloc(E_NUM * 4);
  int*    meta   = (int*)  alloc(160 * 4);
  float*  p_slot = (float*)alloc((size_t)2*N_TOK * 4);
  int*    list   = (int*)  alloc((size_t)E_NUM*N_TOK * 4);
  unsigned short* xb  = (unsigned short*)alloc((size_t)N_TOK*C_DIM * 2);
  unsigned short* wb1 = (unsigned short*)alloc((size_t)E_NUM*C_DIM*F_DIM * 2);
  unsigned short* wb3 = (unsigned short*)alloc((size_t)E_NUM*C_DIM*F_DIM * 2);
  unsigned short* wb2 = (unsigned short*)alloc((size_t)E_NUM*C_DIM*F_DIM * 2);
  unsigned short* h   = (unsigned short*)alloc((size_t)(2*N_TOK + 1024)*F_DIM * 2);

  hipMemsetAsync(cnt, 0, E_NUM * 4, stream);
  hipMemsetAsync(y, 0, (size_t)N_TOK * C_DIM * 4, stream);
  k_cvt_x<<<4096, 256, 0, stream>>>(x, xb, (N_TOK*C_DIM)/4);
  // W1,W3: [E][C][F] -> [E][F][C]
  k_tcvt_w<<<dim3(F_DIM/64, C_DIM/64, E_NUM), dim3(64,4), 0, stream>>>(W1, wb1, C_DIM, F_DIM);
  k_tcvt_w<<<dim3(F_DIM/64, C_DIM/64, E_NUM), dim3(64,4), 0, stream>>>(W3, wb3, C_DIM, F_DIM);
  // W2: [E][F][C] -> [E][C][F]
  k_tcvt_w<<<dim3(C_DIM/64, F_DIM/64, E_NUM), dim3(64,4), 0, stream>>>(W2, wb2, F_DIM, C_DIM);
  k_router<<<N_TOK/4, 256, 0, stream>>>(x, Wg, cnt, list, p_slot);
  k_prefix<<<1, 64, 0, stream>>>(cnt, meta);
  k_gemm1<<<GRID1, 256, 0, stream>>>(xb, wb1, wb3, h, cnt, meta, list);
  k_gemm2<<<GRID2, 256, 0, stream>>>(h, wb2, y, cnt, meta, list, p_slot);
}

// Round 3
// 1828.589 us; speedup vs baseline: 1.2433x; 1.0915x over previous
//
#include <hip/hip_runtime.h>

#define N_TOK 8192
#define C_DIM 2048
#define F_DIM 5632
#define E_NUM 8
#define BK 64

#define BM 256
#define MAXT 72                      // sum ceil(cnt_e/256) <= 16384/256 + 8 = 72
#define BN1 128
#define GRID1 (MAXT * (F_DIM/BN1))   // 72*44 = 3168, /8 = 396
#define BN2 256
#define GRID2 (MAXT * (C_DIM/BN2))   // 72*8 = 576, /8 = 72
#define NT1 (C_DIM/BK)               // 32
#define NT2 (F_DIM/BK)               // 88

typedef __attribute__((ext_vector_type(8))) short bf16x8;
typedef __attribute__((ext_vector_type(4))) float f32x4;

typedef const void __attribute__((address_space(1)))* gas1;
typedef void __attribute__((address_space(3)))* las3;

__device__ __forceinline__ unsigned short f2bf(float f){
  union { float f; unsigned u; } v; v.f = f;
  unsigned r = v.u + 0x7FFFu + ((v.u >> 16) & 1u);   // RNE
  return (unsigned short)(r >> 16);
}

__device__ __forceinline__ void glds16(const unsigned short* g, unsigned short* l){
  __builtin_amdgcn_global_load_lds((gas1)g, (las3)l, 16, 0, 0);
}

#define MFMA_BF16 __builtin_amdgcn_mfma_f32_16x16x32_bf16

// ---------------- x fp32 -> bf16 ----------------
__global__ void k_cvt_x(const float* __restrict__ x, unsigned short* __restrict__ xb, int n4){
  int i = blockIdx.x * blockDim.x + threadIdx.x;
  int stride = gridDim.x * blockDim.x;
  const float4* xi = (const float4*)x;
  ushort4* xo = (ushort4*)xb;
  for (; i < n4; i += stride){
    float4 v = xi[i];
    ushort4 o; o.x = f2bf(v.x); o.y = f2bf(v.y); o.z = f2bf(v.z); o.w = f2bf(v.w);
    xo[i] = o;
  }
}

// ------- weight convert + transpose: in [R][Cc] fp32 -> out [Cc][R] bf16, per z-slab -------
__global__ void k_tcvt_w(const float* __restrict__ in, unsigned short* __restrict__ out, int R, int Cc){
  __shared__ float t[64][65];
  size_t slab = (size_t)blockIdx.z * R * Cc;
  in += slab; out += slab;
  int c0 = blockIdx.x * 64, r0 = blockIdx.y * 64;
  int tx = threadIdx.x, ty = threadIdx.y;     // 64 x 4
  #pragma unroll
  for (int i = 0; i < 16; ++i){
    int r = ty + i*4;
    t[r][tx] = in[(size_t)(r0 + r) * Cc + c0 + tx];
  }
  __syncthreads();
  #pragma unroll
  for (int i = 0; i < 16; ++i){
    int cr = ty + i*4;
    out[(size_t)(c0 + cr) * R + r0 + tx] = f2bf(t[tx][cr]);
  }
}

// ---------------- router ----------------
__global__ void k_router(const float* __restrict__ x, const float* __restrict__ Wg,
                         int* __restrict__ cnt, int* __restrict__ list, float* __restrict__ p_slot)
{
  int wid = threadIdx.x >> 6, lane = threadIdx.x & 63;
  int n = blockIdx.x * 4 + wid;                 // one wave per token
  int e = lane >> 3, sub = lane & 7;
  const float* xr = x + (size_t)n * C_DIM;
  float acc = 0.f;
  for (int i0 = sub*4; i0 < C_DIM; i0 += 32){
    float4 v = *(const float4*)&xr[i0];
    acc += v.x * Wg[(i0  )*E_NUM + e];
    acc += v.y * Wg[(i0+1)*E_NUM + e];
    acc += v.z * Wg[(i0+2)*E_NUM + e];
    acc += v.w * Wg[(i0+3)*E_NUM + e];
  }
  acc += __shfl_xor(acc, 1);
  acc += __shfl_xor(acc, 2);
  acc += __shfl_xor(acc, 4);
  float lg[E_NUM];
  #pragma unroll
  for (int j = 0; j < E_NUM; ++j) lg[j] = __shfl(acc, j*8);
  if (lane == 0){
    int e1 = 0; float m1 = lg[0];
    #pragma unroll
    for (int j = 1; j < E_NUM; ++j) if (lg[j] > m1){ m1 = lg[j]; e1 = j; }
    int e2 = -1; float m2 = -1e30f;
    #pragma unroll
    for (int j = 0; j < E_NUM; ++j) if (j != e1 && lg[j] > m2){ m2 = lg[j]; e2 = j; }
    float p1 = 1.f / (1.f + __expf(m2 - m1));
    float p2 = 1.f - p1;
    int pos1 = atomicAdd(&cnt[e1], 1);
    list[e1*N_TOK + pos1] = n*2;
    p_slot[n*2] = p1;
    int pos2 = atomicAdd(&cnt[e2], 1);
    list[e2*N_TOK + pos2] = n*2 + 1;
    p_slot[n*2 + 1] = p2;
  }
}

// ---------------- prefix / tile table ----------------
__global__ void k_prefix(const int* __restrict__ cnt, int* __restrict__ meta){
  if (threadIdx.x == 0 && blockIdx.x == 0){
    int acc = 0, t = 0;
    for (int e = 0; e < E_NUM; ++e){
      meta[e] = acc; acc += cnt[e];
      int nt = (cnt[e] + BM - 1) / BM;
      for (int i = 0; i < nt; ++i) meta[16 + t++] = (e << 16) | i;
    }
    meta[8] = t;
  }
}

#define PHASE_ENTER() do{ __builtin_amdgcn_sched_barrier(0); __builtin_amdgcn_s_barrier(); \
                          __builtin_amdgcn_s_setprio(1); } while(0)
#define PHASE_EXIT()  do{ __builtin_amdgcn_s_setprio(0); __builtin_amdgcn_sched_barrier(0); \
                          __builtin_amdgcn_s_barrier(); } while(0)

// ---------------- GEMM1: 256x128 dual-B 8-phase, h = silu(x@W1)*(x@W3) ----------------
__global__ __launch_bounds__(512, 2) void k_gemm1(
    const unsigned short* __restrict__ xb,
    const unsigned short* __restrict__ wb1,   // [E][F][C] bf16
    const unsigned short* __restrict__ wb3,   // [E][F][C]
    unsigned short* __restrict__ h,           // [2N+1024][F] bf16
    const int* __restrict__ cnt,
    const int* __restrict__ meta,
    const int* __restrict__ list)
{
  int o = blockIdx.x;
  int w = (o & 7) * (GRID1/8) + (o >> 3);
  int t = w % MAXT;
  int n0 = (w / MAXT) * BN1;
  if (t >= meta[8]) return;
  int info = meta[16 + t];
  int e  = info >> 16;
  int m0 = (info & 0xffff) * BM;
  int count = cnt[e];
  int hbase = meta[e];

  // [2] x { A[256][64] (16384 el), B1[128][64] (8192), B3[128][64] (8192) } = 128 KiB
  __shared__ __align__(16) unsigned short lds[2*32768];

  int tid = threadIdx.x;
  int lane = tid & 63, wid = tid >> 6;
  int wm = wid >> 1, wn = wid & 1;            // 4M x 2N waves, wave tile 64x64
  int l15 = lane & 15;
  int xc0 = (lane >> 4) ^ (lane & 7);         // T2 swizzled k-chunk (k-step 0)
  int xc1 = xc0 ^ 4;                          // k-step 1

  int srow = tid >> 3;                        // staging row within 64-row unit
  int swz = ((tid & 7) ^ (srow & 7)) * 8;     // pre-swizzled source chunk
  const unsigned short* aP[4];
  #pragma unroll
  for (int u = 0; u < 4; ++u){
    int ts = list[e*N_TOK + m0 + u*64 + srow];
    int tok = (ts >> 1) & (N_TOK - 1);
    aP[u] = xb + (size_t)tok * C_DIM + swz;
  }
  const unsigned short* bP[4];                // u: B1h0,B1h1,B3h0,B3h1
  #pragma unroll
  for (int u = 0; u < 4; ++u){
    const unsigned short* base = (u < 2) ? wb1 : wb3;
    bP[u] = base + ((size_t)e*F_DIM + n0 + (u & 1)*64 + srow) * C_DIM + swz;
  }
  int ldw = wid * 512;

  #define ST_A(u, kt) glds16(aP[u] + (kt)*BK, &lds[((kt)&1)*32768 + (u)*4096 + ldw])
  #define ST_B(u, kt) glds16(bP[u] + (kt)*BK, &lds[((kt)&1)*32768 + 16384 + (u)*4096 + ldw])

  // prologue: A(0), B(0), A(1); wait until A(0),B(0) landed (A(1) may pend = 4 loads)
  ST_A(0,0); ST_A(1,0); ST_A(2,0); ST_A(3,0);
  ST_B(0,0); ST_B(1,0); ST_B(2,0); ST_B(3,0);
  ST_A(0,1); ST_A(1,1); ST_A(2,1); ST_A(3,1);
  asm volatile("s_waitcnt vmcnt(4)" ::: "memory");
  __builtin_amdgcn_sched_barrier(0);
  __builtin_amdgcn_s_barrier();

  f32x4 zero = {0.f, 0.f, 0.f, 0.f};
  f32x4 acc1[4][4], acc3[4][4];
  #pragma unroll
  for (int m = 0; m < 4; ++m)
    #pragma unroll
    for (int q = 0; q < 4; ++q){ acc1[m][q] = zero; acc3[m][q] = zero; }

  for (int kt = 0; kt < NT1; ++kt){
    const unsigned short* bufc = &lds[(kt & 1)*32768];
    // ---- phase 0: read all A-frags + B-frag 0; stage B(kt+1) into other buffer ----
    bf16x8 a[4][2], b1f[2], b3f[2];
    #pragma unroll
    for (int m = 0; m < 4; ++m){
      int row = wm*64 + m*16 + l15;
      a[m][0] = *(const bf16x8*)&bufc[row*64 + xc0*8];
      a[m][1] = *(const bf16x8*)&bufc[row*64 + xc1*8];
    }
    {
      int brow = wn*64 + l15;
      b1f[0] = *(const bf16x8*)&bufc[16384 + brow*64 + xc0*8];
      b1f[1] = *(const bf16x8*)&bufc[16384 + brow*64 + xc1*8];
      b3f[0] = *(const bf16x8*)&bufc[24576 + brow*64 + xc0*8];
      b3f[1] = *(const bf16x8*)&bufc[24576 + brow*64 + xc1*8];
    }
    ST_B(0, kt+1); ST_B(1, kt+1); ST_B(2, kt+1); ST_B(3, kt+1);
    PHASE_ENTER();
    #pragma unroll
    for (int m = 0; m < 4; ++m){
      acc1[m][0] = MFMA_BF16(a[m][0], b1f[0], acc1[m][0], 0, 0, 0);
      acc1[m][0] = MFMA_BF16(a[m][1], b1f[1], acc1[m][0], 0, 0, 0);
      acc3[m][0] = MFMA_BF16(a[m][0], b3f[0], acc3[m][0], 0, 0, 0);
      acc3[m][0] = MFMA_BF16(a[m][1], b3f[1], acc3[m][0], 0, 0, 0);
    }
    PHASE_EXIT();
    // ---- phases 1..3: read B-frag q; stage A(kt+2) at p1/p2; boundary vmcnt at p3 ----
    #pragma unroll
    for (int q = 1; q < 4; ++q){
      int brow = wn*64 + q*16 + l15;
      b1f[0] = *(const bf16x8*)&bufc[16384 + brow*64 + xc0*8];
      b1f[1] = *(const bf16x8*)&bufc[16384 + brow*64 + xc1*8];
      b3f[0] = *(const bf16x8*)&bufc[24576 + brow*64 + xc0*8];
      b3f[1] = *(const bf16x8*)&bufc[24576 + brow*64 + xc1*8];
      if (q == 1){ ST_A(0, kt+2); ST_A(1, kt+2); }
      if (q == 2){ ST_A(2, kt+2); ST_A(3, kt+2); }
      PHASE_ENTER();
      #pragma unroll
      for (int m = 0; m < 4; ++m){
        acc1[m][q] = MFMA_BF16(a[m][0], b1f[0], acc1[m][q], 0, 0, 0);
        acc1[m][q] = MFMA_BF16(a[m][1], b1f[1], acc1[m][q], 0, 0, 0);
        acc3[m][q] = MFMA_BF16(a[m][0], b3f[0], acc3[m][q], 0, 0, 0);
        acc3[m][q] = MFMA_BF16(a[m][1], b3f[1], acc3[m][q], 0, 0, 0);
      }
      __builtin_amdgcn_s_setprio(0);
      if (q == 3) asm volatile("s_waitcnt vmcnt(4)" ::: "memory");
      __builtin_amdgcn_sched_barrier(0);
      __builtin_amdgcn_s_barrier();
    }
  }
  asm volatile("s_waitcnt vmcnt(0)" ::: "memory");

  // epilogue: D row=(lane>>4)*4+r, col=lane&15
  #pragma unroll
  for (int m = 0; m < 4; ++m){
    #pragma unroll
    for (int r = 0; r < 4; ++r){
      int rloc = m0 + wm*64 + m*16 + ((lane >> 4) * 4) + r;
      if (rloc < count){
        unsigned short* hrow = h + (size_t)(hbase + rloc) * F_DIM + n0 + wn*64 + l15;
        #pragma unroll
        for (int q = 0; q < 4; ++q){
          float v1 = acc1[m][q][r];
          float v3 = acc3[m][q][r];
          float hv = (v1 / (1.f + __expf(-v1))) * v3;
          hrow[q*16] = f2bf(hv);
        }
      }
    }
  }
  #undef ST_A
  #undef ST_B
}

// ---------------- GEMM2: 256x256 single-B 8-phase, y += p * (h @ W2t) ----------------
__global__ __launch_bounds__(512, 2) void k_gemm2(
    const unsigned short* __restrict__ h,
    const unsigned short* __restrict__ wb2,   // [E][C][F] bf16
    float* __restrict__ y,                    // [N][C] fp32, pre-zeroed
    const int* __restrict__ cnt,
    const int* __restrict__ meta,
    const int* __restrict__ list,
    const float* __restrict__ p_slot)
{
  int o = blockIdx.x;
  int w = (o & 7) * (GRID2/8) + (o >> 3);
  int t = w % MAXT;
  int n0 = (w / MAXT) * BN2;
  if (t >= meta[8]) return;
  int info = meta[16 + t];
  int e  = info >> 16;
  int m0 = (info & 0xffff) * BM;
  int count = cnt[e];
  int hbase = meta[e];

  // [2] x { A[256][64], B[256][64] } = 128 KiB
  __shared__ __align__(16) unsigned short lds[2*32768];

  int tid = threadIdx.x;
  int lane = tid & 63, wid = tid >> 6;
  int wm = wid >> 1, wn = wid & 1;            // 4M x 2N waves, wave tile 64x128
  int l15 = lane & 15;
  int xc0 = (lane >> 4) ^ (lane & 7);
  int xc1 = xc0 ^ 4;

  int srow = tid >> 3;
  int swz = ((tid & 7) ^ (srow & 7)) * 8;
  const unsigned short* aP[4];
  #pragma unroll
  for (int u = 0; u < 4; ++u)
    aP[u] = h + (size_t)(hbase + m0 + u*64 + srow) * F_DIM + swz;
  const unsigned short* bP[4];
  #pragma unroll
  for (int u = 0; u < 4; ++u)
    bP[u] = wb2 + ((size_t)e*C_DIM + n0 + u*64 + srow) * F_DIM + swz;
  int ldw = wid * 512;

  #define ST_A2(u, kt) glds16(aP[u] + (kt)*BK, &lds[((kt)&1)*32768 + (u)*4096 + ldw])
  #define ST_B2(u, kt) glds16(bP[u] + (kt)*BK, &lds[((kt)&1)*32768 + 16384 + (u)*4096 + ldw])

  // prologue: A(0),B(0) [8]; vmcnt(4); A(1),B-U0/U2(1) [6]; vmcnt(6) -> kt0 fully landed
  ST_A2(0,0); ST_A2(1,0); ST_A2(2,0); ST_A2(3,0);
  ST_B2(0,0); ST_B2(1,0); ST_B2(2,0); ST_B2(3,0);
  asm volatile("s_waitcnt vmcnt(4)" ::: "memory");
  ST_A2(0,1); ST_A2(1,1); ST_A2(2,1); ST_A2(3,1);
  ST_B2(0,1); ST_B2(2,1);
  asm volatile("s_waitcnt vmcnt(6)" ::: "memory");
  __builtin_amdgcn_sched_barrier(0);
  __builtin_amdgcn_s_barrier();

  f32x4 zero = {0.f, 0.f, 0.f, 0.f};
  f32x4 acc[4][8];
  #pragma unroll
  for (int m = 0; m < 4; ++m)
    #pragma unroll
    for (int nf = 0; nf < 8; ++nf) acc[m][nf] = zero;

  for (int kt = 0; kt < NT2; ++kt){
    const unsigned short* bufc = &lds[(kt & 1)*32768];
    bf16x8 a[4][2], bf[2][2];
    // ---- phase 0: all A-frags + B-frags 0,1; stage B-U1,U3(kt+1) ----
    #pragma unroll
    for (int m = 0; m < 4; ++m){
      int row = wm*64 + m*16 + l15;
      a[m][0] = *(const bf16x8*)&bufc[row*64 + xc0*8];
      a[m][1] = *(const bf16x8*)&bufc[row*64 + xc1*8];
    }
    #pragma unroll
    for (int j = 0; j < 2; ++j){
      int brow = wn*128 + j*16 + l15;
      bf[j][0] = *(const bf16x8*)&bufc[16384 + brow*64 + xc0*8];
      bf[j][1] = *(const bf16x8*)&bufc[16384 + brow*64 + xc1*8];
    }
    ST_B2(1, kt+1); ST_B2(3, kt+1);
    PHASE_ENTER();
    #pragma unroll
    for (int m = 0; m < 4; ++m)
      #pragma unroll
      for (int j = 0; j < 2; ++j){
        acc[m][j] = MFMA_BF16(a[m][0], bf[j][0], acc[m][j], 0, 0, 0);
        acc[m][j] = MFMA_BF16(a[m][1], bf[j][1], acc[m][j], 0, 0, 0);
      }
    PHASE_EXIT();
    // ---- phases 1..3 ----
    #pragma unroll
    for (int q = 1; q < 4; ++q){
      #pragma unroll
      for (int j = 0; j < 2; ++j){
        int brow = wn*128 + (q*2 + j)*16 + l15;
        bf[j][0] = *(const bf16x8*)&bufc[16384 + brow*64 + xc0*8];
        bf[j][1] = *(const bf16x8*)&bufc[16384 + brow*64 + xc1*8];
      }
      if (q == 1){ ST_A2(0, kt+2); ST_A2(1, kt+2); }
      if (q == 2){ ST_A2(2, kt+2); ST_A2(3, kt+2); }
      if (q == 3){ ST_B2(0, kt+2); ST_B2(2, kt+2); }
      PHASE_ENTER();
      #pragma unroll
      for (int m = 0; m < 4; ++m)
        #pragma unroll
        for (int j = 0; j < 2; ++j){
          acc[m][q*2+j] = MFMA_BF16(a[m][0], bf[j][0], acc[m][q*2+j], 0, 0, 0);
          acc[m][q*2+j] = MFMA_BF16(a[m][1], bf[j][1], acc[m][q*2+j], 0, 0, 0);
        }
      __builtin_amdgcn_s_setprio(0);
      if (q == 3) asm volatile("s_waitcnt vmcnt(6)" ::: "memory");
      __builtin_amdgcn_sched_barrier(0);
      __builtin_amdgcn_s_barrier();
    }
  }
  asm volatile("s_waitcnt vmcnt(0)" ::: "memory");

  // epilogue: two commutative fp32 adds per y element from exact 0 -> deterministic
  #pragma unroll
  for (int m = 0; m < 4; ++m){
    #pragma unroll
    for (int r = 0; r < 4; ++r){
      int rloc = m0 + wm*64 + m*16 + ((lane >> 4) * 4) + r;
      if (rloc < count){
        int ts = list[e*N_TOK + rloc];
        float p = p_slot[ts];
        int tok = ts >> 1;
        float* yr = y + (size_t)tok * C_DIM + n0 + wn*128 + l15;
        #pragma unroll
        for (int nf = 0; nf < 8; ++nf)
          atomicAdd(&yr[nf*16], p * acc[m][nf][r]);
      }
    }
  }
  #undef ST_A2
  #undef ST_B2
}

extern "C" void kernel_launch(void* const* d_in, const int* in_sizes, int n_in,
                              void* d_out, int out_size, void* d_ws, size_t ws_size,
                              hipStream_t stream)
{
  const float* x  = (const float*)d_in[0];
  const float* Wg = (const float*)d_in[1];
  const float* W1 = (const float*)d_in[2];
  const float* W3 = (const float*)d_in[3];
  const float* W2 = (const float*)d_in[4];
  float* y = (float*)d_out;
  (void)in_sizes; (void)n_in; (void)out_size; (void)ws_size;

  char* ws = (char*)d_ws;
  size_t o = 0;
  auto alloc = [&](size_t bytes)->char* {
    char* p = ws + o;
    o = (o + bytes + 255) & ~(size_t)255;
    return p;
  };
  int*    cnt    = (int*)  alloc(E_NUM * 4);
  int*    meta   = (int*)  alloc(160 * 4);
  float*  p_slot = (float*)alloc((size_t)2*N_TOK * 4);
  int*    list   = (int*)  alloc((size_t)E_NUM*N_TOK * 4);
  unsigned short* xb  = (unsigned short*)alloc((size_t)N_TOK*C_DIM * 2);
  unsigned short* wb1 = (unsigned short*)alloc((size_t)E_NUM*C_DIM*F_DIM * 2);
  unsigned short* wb3 = (unsigned short*)alloc((size_t)E_NUM*C_DIM*F_DIM * 2);
  unsigned short* wb2 = (unsigned short*)alloc((size_t)E_NUM*C_DIM*F_DIM * 2);
  unsigned short* h   = (unsigned short*)alloc((size_t)(2*N_TOK + 1024)*F_DIM * 2);

  hipMemsetAsync(cnt, 0, E_NUM * 4, stream);
  hipMemsetAsync(y, 0, (size_t)N_TOK * C_DIM * 4, stream);
  k_cvt_x<<<4096, 256, 0, stream>>>(x, xb, (N_TOK*C_DIM)/4);
  // W1,W3: [E][C][F] -> [E][F][C]
  k_tcvt_w<<<dim3(F_DIM/64, C_DIM/64, E_NUM), dim3(64,4), 0, stream>>>(W1, wb1, C_DIM, F_DIM);
  k_tcvt_w<<<dim3(F_DIM/64, C_DIM/64, E_NUM), dim3(64,4), 0, stream>>>(W3, wb3, C_DIM, F_DIM);
  // W2: [E][F][C] -> [E][C][F]
  k_tcvt_w<<<dim3(C_DIM/64, F_DIM/64, E_NUM), dim3(64,4), 0, stream>>>(W2, wb2, F_DIM, C_DIM);
  k_router<<<N_TOK/4, 256, 0, stream>>>(x, Wg, cnt, list, p_slot);
  k_prefix<<<1, 64, 0, stream>>>(cnt, meta);
  k_gemm1<<<GRID1, 512, 0, stream>>>(xb, wb1, wb3, h, cnt, meta, list);
  k_gemm2<<<GRID2, 512, 0, stream>>>(h, wb2, y, cnt, meta, list, p_slot);
}